// Round 1
// baseline (176.428 us; speedup 1.0000x reference)
//
#include <hip/hip_runtime.h>
#include <math.h>

// Problem constants (fixed-shape problem)
#define BN   2
#define CG   32      // channels per border group (128/4)
#define HH   128
#define WW   128
#define HWSZ (HH*WW) // 16384
#define KK   16384   // boxes per batch = H*W
#define TK   16      // boxes per block in main kernel

// ---------------------------------------------------------------------------
// Kernel 1: transpose feature [8 slabs][C=32][HW=16384] -> ws [8][HW][C]
// so that all 32 channels of one spatial position are contiguous (128B,
// 128B-aligned). Tiled through LDS; coalesced on both sides.
// ---------------------------------------------------------------------------
__global__ __launch_bounds__(256) void transpose_kernel(
    const float* __restrict__ feat, float* __restrict__ ws) {
  __shared__ float lds[64 * 33];           // [i=64][c=32] padded to 33
  const int s  = blockIdx.y;               // slab 0..7  (= b*4+g)
  const int i0 = blockIdx.x * 64;          // spatial tile base
  const int t  = threadIdx.x;

  // Read: lanes sweep consecutive i (coalesced 256B per wave per c)
  const float* src = feat + (size_t)s * (CG * HWSZ);
  const int iw = t & 63;
  const int wq = t >> 6;                   // 0..3
#pragma unroll
  for (int j = 0; j < 8; ++j) {
    const int c = wq + 4 * j;              // covers 0..31
    lds[iw * 33 + c] = src[(size_t)c * HWSZ + i0 + iw];
  }
  __syncthreads();

  // Write: lanes sweep consecutive c (contiguous 256B per wave)
  float* dst = ws + ((size_t)s * HWSZ + i0) * CG;
  const int c2 = t & 31;
  const int ih = t >> 5;                   // 0..7
#pragma unroll
  for (int j = 0; j < 8; ++j) {
    const int i = ih + 8 * j;              // covers 0..63
    dst[i * CG + c2] = lds[i * 33 + c2];
  }
}

// ---------------------------------------------------------------------------
// Kernel 2: main border-align.
// Block = 16 boxes, 128 threads = (g = t>>5 in 0..3) x (c = t&31).
// pos_stride/c_stride parameterize the feature layout:
//   transposed ws : pos_stride=32, c_stride=1     (fast path)
//   original feat : pos_stride=1,  c_stride=16384 (fallback if ws too small)
// ---------------------------------------------------------------------------
__global__ __launch_bounds__(128) void border_align_kernel(
    const float* __restrict__ base, const float* __restrict__ boxes,
    const int* __restrict__ psp, float* __restrict__ out,
    int pos_stride, int c_stride) {
  __shared__ float bxs[TK * 4];
  __shared__ float lmax[CG * 65];          // [c][k*4+g], padded 64->65

  const int blk = blockIdx.x;
  const int b   = blk >> 10;               // 1024 blocks per batch (K/TK)
  const int k0  = (blk & 1023) * TK;
  const int t   = threadIdx.x;
  const int ps  = *psp;                    // pool_size (10)
  const float psf = (float)ps;

  if (t < TK * 4) bxs[t] = boxes[((size_t)b * KK + k0) * 4 + t];
  __syncthreads();

  const int g = t >> 5;                    // border 0..3
  const int c = t & 31;                    // channel
  const float* slab = base + (size_t)(b * 4 + g) * (CG * HWSZ)
                           + (size_t)c * c_stride;

  for (int k = 0; k < TK; ++k) {
    const float x1 = bxs[k * 4 + 0];
    const float y1 = bxs[k * 4 + 1];
    const float x2 = bxs[k * 4 + 2];
    const float y2 = bxs[k * 4 + 3];
    float m = -INFINITY;
    for (int p = 0; p <= ps; ++p) {
      const float tf = (float)p / psf;
      const float sx = x1 + tf * (x2 - x1);
      const float sy = y1 + tf * (y2 - y1);
      float x, y;
      if      (g == 0) { x = sx; y = y1; }   // top
      else if (g == 1) { x = x1; y = sy; }   // left
      else if (g == 2) { x = sx; y = y2; }   // bottom
      else             { x = x2; y = sy; }   // right

      const bool valid = (x > -1.0f) && (x < (float)WW) &&
                         (y > -1.0f) && (y < (float)HH);
      const float xc = fminf(fmaxf(x, 0.0f), (float)(WW - 1));
      const float yc = fminf(fmaxf(y, 0.0f), (float)(HH - 1));
      const int x0 = (int)xc;               // xc >= 0 -> trunc == floor
      const int y0 = (int)yc;
      const float lx = xc - (float)x0;
      const float ly = yc - (float)y0;
      const int x1i = min(x0 + 1, WW - 1);
      const int y1i = min(y0 + 1, HH - 1);

      const float* r0 = slab + (size_t)(y0  * WW) * pos_stride;
      const float* r1 = slab + (size_t)(y1i * WW) * pos_stride;
      const float f00 = r0[x0  * pos_stride];
      const float f01 = r0[x1i * pos_stride];
      const float f10 = r1[x0  * pos_stride];
      const float f11 = r1[x1i * pos_stride];

      const float w00 = (1.0f - ly) * (1.0f - lx);
      const float w01 = (1.0f - ly) * lx;
      const float w10 = ly * (1.0f - lx);
      const float w11 = ly * lx;
      float v = f00 * w00 + f01 * w01 + f10 * w10 + f11 * w11;
      v = valid ? v : 0.0f;
      m = fmaxf(m, v);
    }
    lmax[c * 65 + k * 4 + g] = m;
  }
  __syncthreads();

  // Coalesced write: out[b][c][k][g] = ((b*32+c)*16384 + k)*4 + g.
  // For fixed c, the 16 k x 4 g block is 256 contiguous bytes.
  const int wv = t >> 6;                   // wave 0..1
  const int kg = t & 63;                   // k*4+g within the chunk
#pragma unroll
  for (int it = 0; it < 16; ++it) {
    const int cc = wv + 2 * it;            // covers 0..31
    out[(((size_t)(b * CG + cc)) * KK + k0) * 4 + kg] = lmax[cc * 65 + kg];
  }
}

extern "C" void kernel_launch(void* const* d_in, const int* in_sizes, int n_in,
                              void* d_out, int out_size, void* d_ws, size_t ws_size,
                              hipStream_t stream) {
  const float* feature = (const float*)d_in[0];
  const float* boxes   = (const float*)d_in[1];
  const int*   psp     = (const int*)d_in[2];
  float*       out     = (float*)d_out;

  const size_t need = (size_t)BN * 4 * CG * HWSZ * sizeof(float); // 16 MiB
  if (ws_size >= need) {
    float* ws = (float*)d_ws;
    hipLaunchKernelGGL(transpose_kernel, dim3(HWSZ / 64, BN * 4), dim3(256), 0,
                       stream, feature, ws);
    hipLaunchKernelGGL(border_align_kernel, dim3(BN * (KK / TK)), dim3(128), 0,
                       stream, ws, boxes, psp, out, /*pos_stride=*/CG,
                       /*c_stride=*/1);
  } else {
    // Fallback: gather straight from the original [B,4,C,H,W] layout.
    hipLaunchKernelGGL(border_align_kernel, dim3(BN * (KK / TK)), dim3(128), 0,
                       stream, feature, boxes, psp, out, /*pos_stride=*/1,
                       /*c_stride=*/HWSZ);
  }
}

// Round 2
// 127.290 us; speedup vs baseline: 1.3860x; 1.3860x over previous
//
#include <hip/hip_runtime.h>
#include <math.h>

// Problem constants (fixed-shape problem)
#define BN   2
#define CG   32      // channels per border group (128/4)
#define HH   128
#define WW   128
#define HWSZ (HH*WW) // 16384
#define KK   16384   // boxes per batch
#define TK   32      // boxes per block in main kernel

typedef float vf4 __attribute__((ext_vector_type(4)));

// ---------------------------------------------------------------------------
// Kernel 1: transpose feature [8 slabs][C=32][HW] -> ws [8][HW][C].
// float4 on both global sides; 4x4 register micro-transpose; XOR-swizzled
// LDS (quad q' = q ^ ((i>>2)&7)) so both b128 write and read phases are
// bank-conflict-free.
// ---------------------------------------------------------------------------
__global__ __launch_bounds__(256) void transpose_kernel(
    const float* __restrict__ feat, float* __restrict__ ws) {
  __shared__ vf4 lds4[128 * 8];            // [i=128][8 quads], swizzled
  const int s  = blockIdx.y;               // slab 0..7 (= b*4+g)
  const int i0 = blockIdx.x * 128;         // spatial tile base
  const int t  = threadIdx.x;

  const int iL = (t & 31) * 4;             // 4 consecutive positions
  const int cq = t >> 5;                   // channel quad 0..7
  const int c0 = cq * 4;

  const float* src = feat + (size_t)s * (CG * HWSZ) + i0 + iL;
  vf4 r[4];
#pragma unroll
  for (int cc = 0; cc < 4; ++cc)
    r[cc] = *(const vf4*)(src + (size_t)(c0 + cc) * HWSZ);

#pragma unroll
  for (int ii = 0; ii < 4; ++ii) {         // register transpose + LDS store
    const int i = iL + ii;
    const int q = cq ^ ((i >> 2) & 7);
    vf4 v; v[0] = r[0][ii]; v[1] = r[1][ii]; v[2] = r[2][ii]; v[3] = r[3][ii];
    lds4[i * 8 + q] = v;
  }
  __syncthreads();

  float* dst = ws + ((size_t)s * HWSZ + i0) * CG;
  const int cq2 = t & 7;
#pragma unroll
  for (int it = 0; it < 4; ++it) {
    const int i = (t >> 3) + 32 * it;      // 0..127
    const int q = cq2 ^ ((i >> 2) & 7);
    *(vf4*)(dst + i * CG + cq2 * 4) = lds4[i * 8 + q];
  }
}

// ---------------------------------------------------------------------------
// Kernel 2: main border-align (fast path, transposed layout).
// Block = 32 boxes, 256 threads: cq = t&7 (channel quad), g = (t>>3)&3,
// kk = t>>5 (box lane); each thread does 4 boxes (k = kk + 8*kb), 4 channels
// per float4 gather. Branch-free (mov,fix) axis decomposition; t-table in LDS.
// ---------------------------------------------------------------------------
__global__ __launch_bounds__(256) void border_align_kernel(
    const float* __restrict__ ws, const float* __restrict__ boxes,
    const int* __restrict__ psp, float* __restrict__ out) {
  __shared__ float bxs[TK * 4];
  __shared__ float stf[64];
  __shared__ vf4 lmax4[TK * 4 * 8];        // [kg=k*4+g][8 quads], swizzled

  const int blk = blockIdx.x;
  const int b   = blk >> 9;                // 512 blocks per batch (K/TK)
  const int k0  = (blk & 511) * TK;
  const int t   = threadIdx.x;
  const int ps  = *psp;                    // pool_size (10)

  if (t < TK * 4) bxs[t] = boxes[((size_t)b * KK + k0) * 4 + t];
  if (t < 64 && t <= ps) stf[t] = (float)t / (float)ps;  // exact f32 divide
  __syncthreads();

  const int cq = t & 7;                    // channel quad
  const int g  = (t >> 3) & 3;             // border
  const int kk = t >> 5;                   // box lane 0..7
  const bool horiz = (g & 1) == 0;         // g0/g2: x moves; g1/g3: y moves
  const int mshift = horiz ? 0 : 7;        // mov coordinate * (1 or 128)
  const int fshift = horiz ? 7 : 0;        // fix coordinate * (128 or 1)

  const float* slab = ws + (size_t)(b * 4 + g) * (HWSZ * CG) + cq * 4;

  float mov_s[4], mov_d[4], lf_[4];
  int   bf0_[4], bf1_[4];
  bool  fok[4];
  vf4   acc[4];
#pragma unroll
  for (int kb = 0; kb < 4; ++kb) {
    const int k = kk + 8 * kb;
    const float x1 = bxs[k * 4 + 0], y1 = bxs[k * 4 + 1];
    const float x2 = bxs[k * 4 + 2], y2 = bxs[k * 4 + 3];
    float fix;
    if (horiz) { mov_s[kb] = x1; mov_d[kb] = x2 - x1; fix = (g == 0) ? y1 : y2; }
    else       { mov_s[kb] = y1; mov_d[kb] = y2 - y1; fix = (g == 1) ? x1 : x2; }
    fok[kb] = (fix > -1.0f) && (fix < 128.0f);
    const float fc = fminf(fmaxf(fix, 0.0f), 127.0f);
    const int f0 = (int)fc;
    lf_[kb] = fc - (float)f0;
    const int f1 = min(f0 + 1, 127);
    bf0_[kb] = f0 << fshift;
    bf1_[kb] = f1 << fshift;
    vf4 z; z[0] = z[1] = z[2] = z[3] = -INFINITY;
    acc[kb] = z;
  }

  for (int p = 0; p <= ps; ++p) {
    const float tf = stf[p];
#pragma unroll
    for (int kb = 0; kb < 4; ++kb) {
      const float mov = fmaf(tf, mov_d[kb], mov_s[kb]);
      const bool ok = fok[kb] && (mov > -1.0f) && (mov < 128.0f);
      const float mc = fminf(fmaxf(mov, 0.0f), 127.0f);
      const int m0 = (int)mc;
      const float lm = mc - (float)m0;
      const int m1 = min(m0 + 1, 127);
      const int bm0 = m0 << mshift;
      const int bm1 = m1 << mshift;
      const vf4 f00 = *(const vf4*)(slab + ((bf0_[kb] + bm0) << 5));
      const vf4 f01 = *(const vf4*)(slab + ((bf0_[kb] + bm1) << 5));
      const vf4 f10 = *(const vf4*)(slab + ((bf1_[kb] + bm0) << 5));
      const vf4 f11 = *(const vf4*)(slab + ((bf1_[kb] + bm1) << 5));
      const float lf = lf_[kb];
      const float w00 = (1.0f - lf) * (1.0f - lm);
      const float w01 = (1.0f - lf) * lm;
      const float w10 = lf * (1.0f - lm);
      const float w11 = lf * lm;
      vf4 v = f00 * w00 + f01 * w01 + f10 * w10 + f11 * w11;
      vf4 zz; zz[0] = zz[1] = zz[2] = zz[3] = 0.0f;
      v = ok ? v : zz;
      acc[kb] = __builtin_elementwise_max(acc[kb], v);
    }
  }

  // Stage results: lmax[kg][c] swizzled (quad q' = cq ^ ((kg>>2)&7)).
#pragma unroll
  for (int kb = 0; kb < 4; ++kb) {
    const int kg = (kk + 8 * kb) * 4 + g;
    const int q = cq ^ ((kg >> 2) & 7);
    lmax4[kg * 8 + q] = acc[kb];
  }
  __syncthreads();

  // Coalesced write: out[b][c][k0..k0+31][g]: per c a 512B contiguous run.
  const float* lmaxf = (const float*)lmax4;
  const int kgq = t & 31;                  // float4 index along kg
  const int cb  = t >> 5;                  // 0..7
  float* obase = out + (size_t)b * CG * KK * 4 + (size_t)k0 * 4;
#pragma unroll
  for (int it = 0; it < 4; ++it) {
    const int c = cb + 8 * it;             // 0..31
    vf4 v;
#pragma unroll
    for (int j = 0; j < 4; ++j) {
      const int kg = kgq * 4 + j;
      const int q = (c >> 2) ^ ((kg >> 2) & 7);
      v[j] = lmaxf[kg * 32 + q * 4 + (c & 3)];
    }
    *(vf4*)(obase + (size_t)c * KK * 4 + kgq * 4) = v;
  }
}

// ---------------------------------------------------------------------------
// Fallback (ws too small): scalar gather straight from [B,4,C,H,W].
// ---------------------------------------------------------------------------
__global__ __launch_bounds__(128) void border_align_fallback(
    const float* __restrict__ base, const float* __restrict__ boxes,
    const int* __restrict__ psp, float* __restrict__ out) {
  const int blk = blockIdx.x;
  const int b = blk >> 10;
  const int k = ((blk & 1023) * 16) + (threadIdx.x >> 3);  // 16 boxes/block? no:
  // simple mapping: one thread per (k-sub, g, c) is too big; do 1 thread per
  // (g,c) x 16 boxes like round 1:
  const int t = threadIdx.x;
  const int g = t >> 5, c = t & 31;
  const int k0 = (blk & 1023) * 16;
  const int ps = *psp;
  const float psf = (float)ps;
  const float* slab = base + (size_t)(b * 4 + g) * (CG * HWSZ) + (size_t)c * HWSZ;
  for (int kk = 0; kk < 16; ++kk) {
    const int kbox = k0 + kk;
    const float x1 = boxes[((size_t)b * KK + kbox) * 4 + 0];
    const float y1 = boxes[((size_t)b * KK + kbox) * 4 + 1];
    const float x2 = boxes[((size_t)b * KK + kbox) * 4 + 2];
    const float y2 = boxes[((size_t)b * KK + kbox) * 4 + 3];
    float m = -INFINITY;
    for (int p = 0; p <= ps; ++p) {
      const float tf = (float)p / psf;
      float x, y;
      if      (g == 0) { x = x1 + tf * (x2 - x1); y = y1; }
      else if (g == 1) { x = x1; y = y1 + tf * (y2 - y1); }
      else if (g == 2) { x = x1 + tf * (x2 - x1); y = y2; }
      else             { x = x2; y = y1 + tf * (y2 - y1); }
      const bool valid = (x > -1.0f) && (x < 128.0f) && (y > -1.0f) && (y < 128.0f);
      const float xc = fminf(fmaxf(x, 0.0f), 127.0f);
      const float yc = fminf(fmaxf(y, 0.0f), 127.0f);
      const int x0 = (int)xc, y0 = (int)yc;
      const float lx = xc - (float)x0, ly = yc - (float)y0;
      const int x1i = min(x0 + 1, 127), y1i = min(y0 + 1, 127);
      const float f00 = slab[y0 * WW + x0],  f01 = slab[y0 * WW + x1i];
      const float f10 = slab[y1i * WW + x0], f11 = slab[y1i * WW + x1i];
      float v = f00 * (1 - ly) * (1 - lx) + f01 * (1 - ly) * lx
              + f10 * ly * (1 - lx) + f11 * ly * lx;
      v = valid ? v : 0.0f;
      m = fmaxf(m, v);
    }
    (void)k;
    out[(((size_t)(b * CG + c)) * KK + kbox) * 4 + g] = m;
  }
}

extern "C" void kernel_launch(void* const* d_in, const int* in_sizes, int n_in,
                              void* d_out, int out_size, void* d_ws, size_t ws_size,
                              hipStream_t stream) {
  const float* feature = (const float*)d_in[0];
  const float* boxes   = (const float*)d_in[1];
  const int*   psp     = (const int*)d_in[2];
  float*       out     = (float*)d_out;

  const size_t need = (size_t)BN * 4 * CG * HWSZ * sizeof(float); // 16 MiB
  if (ws_size >= need) {
    float* ws = (float*)d_ws;
    hipLaunchKernelGGL(transpose_kernel, dim3(HWSZ / 128, BN * 4), dim3(256), 0,
                       stream, feature, ws);
    hipLaunchKernelGGL(border_align_kernel, dim3(BN * (KK / TK)), dim3(256), 0,
                       stream, ws, boxes, psp, out);
  } else {
    hipLaunchKernelGGL(border_align_fallback, dim3(BN * (KK / 16)), dim3(128), 0,
                       stream, feature, boxes, psp, out);
  }
}

// Round 3
// 102.760 us; speedup vs baseline: 1.7169x; 1.2387x over previous
//
#include <hip/hip_runtime.h>
#include <math.h>

// Problem constants (fixed-shape problem)
#define BN   2
#define CG   32      // channels per border group (128/4)
#define HH   128
#define WW   128
#define HWSZ (HH*WW) // 16384
#define KK   16384   // boxes per batch
#define TK   16      // boxes per block in main kernel

typedef float vf4 __attribute__((ext_vector_type(4)));

// round-to-nearest-even f32 -> bf16, pack two into one uint (a=low, b=high)
__device__ inline unsigned int pack_bf16(float a, float b) {
  unsigned int ua = __float_as_uint(a);
  unsigned int ub = __float_as_uint(b);
  ua = (ua + 0x7fffu + ((ua >> 16) & 1u)) >> 16;
  ub = (ub + 0x7fffu + ((ub >> 16) & 1u));
  return (ua & 0xffffu) | (ub & 0xffff0000u);
}

// unpack 4 packed bf16 (uint2) -> float4; v[0] = low ushort of q.x
__device__ inline vf4 unpack4(uint2 q) {
  vf4 v;
  v[0] = __uint_as_float(q.x << 16);
  v[1] = __uint_as_float(q.x & 0xffff0000u);
  v[2] = __uint_as_float(q.y << 16);
  v[3] = __uint_as_float(q.y & 0xffff0000u);
  return v;
}

// ---------------------------------------------------------------------------
// Kernel 1: transpose+quantize feature [8 slabs][C=32][HW] -> ws bf16 [8][HW][C].
// All 32 channels of one spatial position become one 64B cache line.
// ---------------------------------------------------------------------------
__global__ __launch_bounds__(256) void transpose_bf16_kernel(
    const float* __restrict__ feat, unsigned short* __restrict__ ws) {
  __shared__ uint2 lds[128 * 9];           // [i=128][8 quads + 1 pad]
  const int s  = blockIdx.y;               // slab 0..7 (= b*4+g)
  const int i0 = blockIdx.x * 128;         // spatial tile base
  const int t  = threadIdx.x;

  const int iL = (t & 31) * 4;             // 4 consecutive positions
  const int cq = t >> 5;                   // channel quad 0..7

  const float* src = feat + (size_t)s * (CG * HWSZ) + i0 + iL;
  vf4 r[4];
#pragma unroll
  for (int cc = 0; cc < 4; ++cc)
    r[cc] = *(const vf4*)(src + (size_t)(cq * 4 + cc) * HWSZ);

#pragma unroll
  for (int ii = 0; ii < 4; ++ii) {         // register micro-transpose + pack
    uint2 q;
    q.x = pack_bf16(r[0][ii], r[1][ii]);
    q.y = pack_bf16(r[2][ii], r[3][ii]);
    lds[(iL + ii) * 9 + cq] = q;
  }
  __syncthreads();

  uint2* dst = (uint2*)(ws + ((size_t)s * HWSZ + i0) * CG);
  const int q2 = t & 7;
  const int ih = t >> 3;                   // 0..31
#pragma unroll
  for (int it = 0; it < 4; ++it) {
    const int i = ih + 32 * it;            // 0..127
    dst[i * 8 + q2] = lds[i * 9 + q2];     // 512B contiguous per wave
  }
}

// ---------------------------------------------------------------------------
// Kernel 2: main border-align (bf16 transposed layout).
// Block = 16 boxes, 256 threads: cq = t&7 (channel quad), g = (t>>3)&3,
// kk = t>>5 (box lane, 2 boxes each). 8B gather per corner serves 4 channels.
// ---------------------------------------------------------------------------
__global__ __launch_bounds__(256) void border_align_kernel(
    const unsigned short* __restrict__ ws, const float* __restrict__ boxes,
    const int* __restrict__ psp, float* __restrict__ out) {
  __shared__ float bxs[TK * 4];
  __shared__ float stf[64];
  __shared__ float lmax[TK * 4 * 33];      // [kg=k*4+g][c], stride 33

  const int blk = blockIdx.x;
  const int b   = blk >> 10;               // 1024 blocks per batch (K/TK)
  const int k0  = (blk & 1023) * TK;
  const int t   = threadIdx.x;
  const int ps  = *psp;                    // pool_size (10)

  if (t < TK * 4) bxs[t] = boxes[((size_t)b * KK + k0) * 4 + t];
  if (t < 64 && t <= ps) stf[t] = (float)t / (float)ps;  // exact f32 divide
  __syncthreads();

  const int cq = t & 7;                    // channel quad
  const int g  = (t >> 3) & 3;             // border
  const int kk = t >> 5;                   // box lane 0..7
  const bool horiz = (g & 1) == 0;         // g0/g2: x moves; g1/g3: y moves
  const int mshift = horiz ? 0 : 7;        // mov coordinate * (1 or 128)
  const int fshift = horiz ? 7 : 0;        // fix coordinate * (128 or 1)

  const unsigned short* slab =
      ws + (size_t)(b * 4 + g) * (HWSZ * CG) + cq * 4;

  float mov_s[2], mov_d[2], lf_[2];
  int   bf0_[2], bf1_[2];
  bool  fok[2];
  vf4   acc[2];
#pragma unroll
  for (int kb = 0; kb < 2; ++kb) {
    const int k = kk + 8 * kb;
    const float x1 = bxs[k * 4 + 0], y1 = bxs[k * 4 + 1];
    const float x2 = bxs[k * 4 + 2], y2 = bxs[k * 4 + 3];
    float fix;
    if (horiz) { mov_s[kb] = x1; mov_d[kb] = x2 - x1; fix = (g == 0) ? y1 : y2; }
    else       { mov_s[kb] = y1; mov_d[kb] = y2 - y1; fix = (g == 1) ? x1 : x2; }
    fok[kb] = (fix > -1.0f) && (fix < 128.0f);
    const float fc = fminf(fmaxf(fix, 0.0f), 127.0f);
    const int f0 = (int)fc;
    lf_[kb] = fc - (float)f0;
    const int f1 = min(f0 + 1, 127);
    bf0_[kb] = f0 << fshift;
    bf1_[kb] = f1 << fshift;
    vf4 z; z[0] = z[1] = z[2] = z[3] = -INFINITY;
    acc[kb] = z;
  }

  for (int p = 0; p <= ps; ++p) {
    const float tf = stf[p];
#pragma unroll
    for (int kb = 0; kb < 2; ++kb) {
      const float mov = fmaf(tf, mov_d[kb], mov_s[kb]);
      const bool ok = fok[kb] && (mov > -1.0f) && (mov < 128.0f);
      const float mc = fminf(fmaxf(mov, 0.0f), 127.0f);
      const int m0 = (int)mc;
      const float lm = mc - (float)m0;
      const int m1 = min(m0 + 1, 127);
      const int p00 = bf0_[kb] + (m0 << mshift);
      const int p01 = bf0_[kb] + (m1 << mshift);
      const int p10 = bf1_[kb] + (m0 << mshift);
      const int p11 = bf1_[kb] + (m1 << mshift);
      const uint2 q00 = *(const uint2*)(slab + (size_t)p00 * CG);
      const uint2 q01 = *(const uint2*)(slab + (size_t)p01 * CG);
      const uint2 q10 = *(const uint2*)(slab + (size_t)p10 * CG);
      const uint2 q11 = *(const uint2*)(slab + (size_t)p11 * CG);
      const float lf = lf_[kb];
      const float w00 = (1.0f - lf) * (1.0f - lm);
      const float w01 = (1.0f - lf) * lm;
      const float w10 = lf * (1.0f - lm);
      const float w11 = lf * lm;
      vf4 v = unpack4(q00) * w00 + unpack4(q01) * w01
            + unpack4(q10) * w10 + unpack4(q11) * w11;
      vf4 zz; zz[0] = zz[1] = zz[2] = zz[3] = 0.0f;
      v = ok ? v : zz;
      acc[kb] = __builtin_elementwise_max(acc[kb], v);
    }
  }

  // Stage results: lmax[kg][c], stride 33 (2-way max on later reads = free).
#pragma unroll
  for (int kb = 0; kb < 2; ++kb) {
    const int kg = (kk + 8 * kb) * 4 + g;
#pragma unroll
    for (int j = 0; j < 4; ++j)
      lmax[kg * 33 + cq * 4 + j] = acc[kb][j];
  }
  __syncthreads();

  // Coalesced write: out[b][c][k0..k0+15][g]: per c a 256B contiguous run.
  const int kgq = t & 15;                  // float4 index along kg (0..15)
  const int cb  = t >> 4;                  // 0..15
#pragma unroll
  for (int it = 0; it < 2; ++it) {
    const int c = cb + 16 * it;            // 0..31
    vf4 v;
#pragma unroll
    for (int j = 0; j < 4; ++j)
      v[j] = lmax[(kgq * 4 + j) * 33 + c];
    *(vf4*)(out + ((size_t)(b * CG + c) * KK + k0) * 4 + kgq * 4) = v;
  }
}

// ---------------------------------------------------------------------------
// Fallback (ws too small): scalar gather straight from [B,4,C,H,W].
// ---------------------------------------------------------------------------
__global__ __launch_bounds__(128) void border_align_fallback(
    const float* __restrict__ base, const float* __restrict__ boxes,
    const int* __restrict__ psp, float* __restrict__ out) {
  const int blk = blockIdx.x;
  const int b = blk >> 10;
  const int t = threadIdx.x;
  const int g = t >> 5, c = t & 31;
  const int k0 = (blk & 1023) * 16;
  const int ps = *psp;
  const float psf = (float)ps;
  const float* slab = base + (size_t)(b * 4 + g) * (CG * HWSZ) + (size_t)c * HWSZ;
  for (int kk = 0; kk < 16; ++kk) {
    const int kbox = k0 + kk;
    const float x1 = boxes[((size_t)b * KK + kbox) * 4 + 0];
    const float y1 = boxes[((size_t)b * KK + kbox) * 4 + 1];
    const float x2 = boxes[((size_t)b * KK + kbox) * 4 + 2];
    const float y2 = boxes[((size_t)b * KK + kbox) * 4 + 3];
    float m = -INFINITY;
    for (int p = 0; p <= ps; ++p) {
      const float tf = (float)p / psf;
      float x, y;
      if      (g == 0) { x = x1 + tf * (x2 - x1); y = y1; }
      else if (g == 1) { x = x1; y = y1 + tf * (y2 - y1); }
      else if (g == 2) { x = x1 + tf * (x2 - x1); y = y2; }
      else             { x = x2; y = y1 + tf * (y2 - y1); }
      const bool valid = (x > -1.0f) && (x < 128.0f) && (y > -1.0f) && (y < 128.0f);
      const float xc = fminf(fmaxf(x, 0.0f), 127.0f);
      const float yc = fminf(fmaxf(y, 0.0f), 127.0f);
      const int x0 = (int)xc, y0 = (int)yc;
      const float lx = xc - (float)x0, ly = yc - (float)y0;
      const int x1i = min(x0 + 1, 127), y1i = min(y0 + 1, 127);
      const float f00 = slab[y0 * WW + x0],  f01 = slab[y0 * WW + x1i];
      const float f10 = slab[y1i * WW + x0], f11 = slab[y1i * WW + x1i];
      float v = f00 * (1 - ly) * (1 - lx) + f01 * (1 - ly) * lx
              + f10 * ly * (1 - lx) + f11 * ly * lx;
      v = valid ? v : 0.0f;
      m = fmaxf(m, v);
    }
    out[(((size_t)(b * CG + c)) * KK + kbox) * 4 + g] = m;
  }
}

extern "C" void kernel_launch(void* const* d_in, const int* in_sizes, int n_in,
                              void* d_out, int out_size, void* d_ws, size_t ws_size,
                              hipStream_t stream) {
  const float* feature = (const float*)d_in[0];
  const float* boxes   = (const float*)d_in[1];
  const int*   psp     = (const int*)d_in[2];
  float*       out     = (float*)d_out;

  const size_t need = (size_t)BN * 4 * CG * HWSZ * sizeof(unsigned short); // 8 MiB
  if (ws_size >= need) {
    unsigned short* ws = (unsigned short*)d_ws;
    hipLaunchKernelGGL(transpose_bf16_kernel, dim3(HWSZ / 128, BN * 4),
                       dim3(256), 0, stream, feature, ws);
    hipLaunchKernelGGL(border_align_kernel, dim3(BN * (KK / TK)), dim3(256), 0,
                       stream, ws, boxes, psp, out);
  } else {
    hipLaunchKernelGGL(border_align_fallback, dim3(BN * (KK / 16)), dim3(128), 0,
                       stream, feature, boxes, psp, out);
  }
}

// Round 5
// 97.438 us; speedup vs baseline: 1.8107x; 1.0546x over previous
//
#include <hip/hip_runtime.h>
#include <math.h>

// Problem constants (fixed-shape problem)
#define BN   2
#define CG   32      // channels per border group (128/4)
#define HH   128
#define WW   128
#define HWSZ (HH*WW) // 16384
#define KK   16384   // boxes per batch
#define TK   16      // boxes per block in main kernel

typedef float vf4 __attribute__((ext_vector_type(4)));
typedef _Float16 h8 __attribute__((ext_vector_type(8)));

// pack two f32 -> fp16 pair (RNE via v_cvt_f16_f32), a=low b=high
__device__ inline unsigned int pack_h2(float a, float b) {
  unsigned short ua = __builtin_bit_cast(unsigned short, (_Float16)a);
  unsigned short ub = __builtin_bit_cast(unsigned short, (_Float16)b);
  return (unsigned int)ua | ((unsigned int)ub << 16);
}

// ---------------------------------------------------------------------------
// Kernel 1: transpose+quantize feature [8 slabs][C=32][HW] -> ws fp16 [8][HW][C].
// All 32 channels of one spatial position become one 64B cache line.
// ---------------------------------------------------------------------------
__global__ __launch_bounds__(256) void transpose_f16_kernel(
    const float* __restrict__ feat, unsigned short* __restrict__ ws) {
  __shared__ uint2 lds[128 * 9];           // [i=128][8 quads + 1 pad]
  const int s  = blockIdx.y;               // slab 0..7 (= b*4+g)
  const int i0 = blockIdx.x * 128;         // spatial tile base
  const int t  = threadIdx.x;

  const int iL = (t & 31) * 4;             // 4 consecutive positions
  const int cq = t >> 5;                   // channel quad 0..7

  const float* src = feat + (size_t)s * (CG * HWSZ) + i0 + iL;
  vf4 r[4];
#pragma unroll
  for (int cc = 0; cc < 4; ++cc)
    r[cc] = *(const vf4*)(src + (size_t)(cq * 4 + cc) * HWSZ);

#pragma unroll
  for (int ii = 0; ii < 4; ++ii) {         // register micro-transpose + pack
    uint2 q;
    q.x = pack_h2(r[0][ii], r[1][ii]);
    q.y = pack_h2(r[2][ii], r[3][ii]);
    lds[(iL + ii) * 9 + cq] = q;
  }
  __syncthreads();

  uint2* dst = (uint2*)(ws + ((size_t)s * HWSZ + i0) * CG);
  const int q2 = t & 7;
  const int ih = t >> 3;                   // 0..31
#pragma unroll
  for (int it = 0; it < 4; ++it) {
    const int i = ih + 32 * it;            // 0..127
    dst[i * 8 + q2] = lds[i * 9 + q2];     // 512B contiguous per wave
  }
}

// ---------------------------------------------------------------------------
// Kernel 2: main border-align (fp16 transposed layout).
// Block = 16 boxes, 256 threads = 4 waves; wave w handles border g=w
// (wave-uniform). Lane = oct (t&3, 8 channels) x kk (lane>>2, box 0..15).
// Per corner: 4 lanes x 16B = one 64B line. Bilinear+max in packed fp16.
// ---------------------------------------------------------------------------
__global__ __launch_bounds__(256) void border_align_kernel(
    const unsigned short* __restrict__ wsu, const float* __restrict__ boxes,
    const int* __restrict__ psp, float* __restrict__ out) {
  __shared__ float bxs[TK * 4];
  __shared__ float stf[64];
  __shared__ float lmax[TK * 4 * 33];      // [kg=k*4+g][c], stride 33

  const int blk = blockIdx.x;
  const int b   = blk >> 10;               // 1024 blocks per batch (K/TK)
  const int k0  = (blk & 1023) * TK;
  const int t   = threadIdx.x;
  const int ps  = *psp;                    // pool_size (10)

  if (t < TK * 4) bxs[t] = boxes[((size_t)b * KK + k0) * 4 + t];
  if (t < 64 && t <= ps) stf[t] = (float)t / (float)ps;  // exact f32 divide
  __syncthreads();

  const int g   = t >> 6;                  // border 0..3 (wave-uniform)
  const int oct = t & 3;                   // channel oct (8 channels)
  const int kk  = (t >> 2) & 15;           // box 0..15
  const bool horiz = (g & 1) == 0;         // g0/g2: x moves; g1/g3: y moves
  const int mshift = horiz ? 0 : 7;        // mov coordinate * (1 or 128)
  const int fshift = horiz ? 7 : 0;        // fix coordinate * (128 or 1)

  const _Float16* slab = (const _Float16*)wsu
      + (size_t)(b * 4 + g) * (HWSZ * CG) + oct * 8;

  const float x1 = bxs[kk * 4 + 0], y1 = bxs[kk * 4 + 1];
  const float x2 = bxs[kk * 4 + 2], y2 = bxs[kk * 4 + 3];
  float mov_s, mov_d, fix;
  if (horiz) { mov_s = x1; mov_d = x2 - x1; fix = (g == 0) ? y1 : y2; }
  else       { mov_s = y1; mov_d = y2 - y1; fix = (g == 1) ? x1 : x2; }
  const bool fok = (fix > -1.0f) && (fix < 128.0f);
  const float fc = fminf(fmaxf(fix, 0.0f), 127.0f);
  const int f0 = (int)fc;
  const float lf = fc - (float)f0;
  const int f1 = min(f0 + 1, 127);
  const int bf0 = f0 << fshift;
  const int bf1 = f1 << fshift;

  h8 acc = (h8)(_Float16)(-65504.0f);      // -inf surrogate (max finite fp16)

  // per-sample address/weight computation
  float lm_c; bool ok_c; int bm0_c, bm1_c;
  auto coords = [&](int p, int& bm0, int& bm1, float& lm, bool& ok) {
    const float mov = fmaf(stf[p], mov_d, mov_s);
    ok = fok && (mov > -1.0f) && (mov < 128.0f);
    const float mc = fminf(fmaxf(mov, 0.0f), 127.0f);
    const int m0 = (int)mc;
    lm = mc - (float)m0;
    const int m1 = min(m0 + 1, 127);
    bm0 = m0 << mshift;
    bm1 = m1 << mshift;
  };

  coords(0, bm0_c, bm1_c, lm_c, ok_c);
  h8 q00 = *(const h8*)(slab + ((size_t)(bf0 + bm0_c) << 5));
  h8 q01 = *(const h8*)(slab + ((size_t)(bf0 + bm1_c) << 5));
  h8 q10 = *(const h8*)(slab + ((size_t)(bf1 + bm0_c) << 5));
  h8 q11 = *(const h8*)(slab + ((size_t)(bf1 + bm1_c) << 5));

  for (int p = 0; p <= ps; ++p) {
    const float lm = lm_c;
    const bool ok = ok_c;
    h8 f00 = q00, f01 = q01, f10 = q10, f11 = q11;
    if (p < ps) {                          // prefetch next sample's corners
      coords(p + 1, bm0_c, bm1_c, lm_c, ok_c);
      q00 = *(const h8*)(slab + ((size_t)(bf0 + bm0_c) << 5));
      q01 = *(const h8*)(slab + ((size_t)(bf0 + bm1_c) << 5));
      q10 = *(const h8*)(slab + ((size_t)(bf1 + bm0_c) << 5));
      q11 = *(const h8*)(slab + ((size_t)(bf1 + bm1_c) << 5));
    }
    const _Float16 w00 = (_Float16)((1.0f - lf) * (1.0f - lm));
    const _Float16 w01 = (_Float16)((1.0f - lf) * lm);
    const _Float16 w10 = (_Float16)(lf * (1.0f - lm));
    const _Float16 w11 = (_Float16)(lf * lm);
    h8 v = f00 * w00 + f01 * w01 + f10 * w10 + f11 * w11;  // v_pk_fma_f16
    v = ok ? v : (h8)(_Float16)0.0f;
    acc = __builtin_elementwise_max(acc, v);               // v_pk_max_f16
  }

  // Stage results as f32: lmax[kg][c], stride 33.  (R4 bug was here: a
  // spurious fmaxf(.,0) clamped negative maxima — store the value as-is.)
  const int kg = kk * 4 + g;
#pragma unroll
  for (int j = 0; j < 8; ++j)
    lmax[kg * 33 + oct * 8 + j] = (float)acc[j];
  __syncthreads();

  // Coalesced write: out[b][c][k0..k0+15][g]: per c a 256B contiguous run.
  const int kgq = t & 15;                  // float4 index along kg (0..15)
  const int cb  = t >> 4;                  // 0..15
#pragma unroll
  for (int it = 0; it < 2; ++it) {
    const int c = cb + 16 * it;            // 0..31
    vf4 v;
#pragma unroll
    for (int j = 0; j < 4; ++j)
      v[j] = lmax[(kgq * 4 + j) * 33 + c];
    *(vf4*)(out + ((size_t)(b * CG + c) * KK + k0) * 4 + kgq * 4) = v;
  }
}

// ---------------------------------------------------------------------------
// Fallback (ws too small): scalar gather straight from [B,4,C,H,W].
// ---------------------------------------------------------------------------
__global__ __launch_bounds__(128) void border_align_fallback(
    const float* __restrict__ base, const float* __restrict__ boxes,
    const int* __restrict__ psp, float* __restrict__ out) {
  const int blk = blockIdx.x;
  const int b = blk >> 10;
  const int t = threadIdx.x;
  const int g = t >> 5, c = t & 31;
  const int k0 = (blk & 1023) * 16;
  const int ps = *psp;
  const float psf = (float)ps;
  const float* slab = base + (size_t)(b * 4 + g) * (CG * HWSZ) + (size_t)c * HWSZ;
  for (int kk = 0; kk < 16; ++kk) {
    const int kbox = k0 + kk;
    const float x1 = boxes[((size_t)b * KK + kbox) * 4 + 0];
    const float y1 = boxes[((size_t)b * KK + kbox) * 4 + 1];
    const float x2 = boxes[((size_t)b * KK + kbox) * 4 + 2];
    const float y2 = boxes[((size_t)b * KK + kbox) * 4 + 3];
    float m = -INFINITY;
    for (int p = 0; p <= ps; ++p) {
      const float tf = (float)p / psf;
      float x, y;
      if      (g == 0) { x = x1 + tf * (x2 - x1); y = y1; }
      else if (g == 1) { x = x1; y = y1 + tf * (y2 - y1); }
      else if (g == 2) { x = x1 + tf * (x2 - x1); y = y2; }
      else             { x = x2; y = y1 + tf * (y2 - y1); }
      const bool valid = (x > -1.0f) && (x < 128.0f) && (y > -1.0f) && (y < 128.0f);
      const float xc = fminf(fmaxf(x, 0.0f), 127.0f);
      const float yc = fminf(fmaxf(y, 0.0f), 127.0f);
      const int x0 = (int)xc, y0 = (int)yc;
      const float lx = xc - (float)x0, ly = yc - (float)y0;
      const int x1i = min(x0 + 1, 127), y1i = min(y0 + 1, 127);
      const float f00 = slab[y0 * WW + x0],  f01 = slab[y0 * WW + x1i];
      const float f10 = slab[y1i * WW + x0], f11 = slab[y1i * WW + x1i];
      float v = f00 * (1 - ly) * (1 - lx) + f01 * (1 - ly) * lx
              + f10 * ly * (1 - lx) + f11 * ly * lx;
      v = valid ? v : 0.0f;
      m = fmaxf(m, v);
    }
    out[(((size_t)(b * CG + c)) * KK + kbox) * 4 + g] = m;
  }
}

extern "C" void kernel_launch(void* const* d_in, const int* in_sizes, int n_in,
                              void* d_out, int out_size, void* d_ws, size_t ws_size,
                              hipStream_t stream) {
  const float* feature = (const float*)d_in[0];
  const float* boxes   = (const float*)d_in[1];
  const int*   psp     = (const int*)d_in[2];
  float*       out     = (float*)d_out;

  const size_t need = (size_t)BN * 4 * CG * HWSZ * sizeof(unsigned short); // 8 MiB
  if (ws_size >= need) {
    unsigned short* ws = (unsigned short*)d_ws;
    hipLaunchKernelGGL(transpose_f16_kernel, dim3(HWSZ / 128, BN * 4),
                       dim3(256), 0, stream, feature, ws);
    hipLaunchKernelGGL(border_align_kernel, dim3(BN * (KK / TK)), dim3(256), 0,
                       stream, ws, boxes, psp, out);
  } else {
    hipLaunchKernelGGL(border_align_fallback, dim3(BN * (KK / 16)), dim3(128), 0,
                       stream, feature, boxes, psp, out);
  }
}

// Round 6
// 96.502 us; speedup vs baseline: 1.8282x; 1.0097x over previous
//
#include <hip/hip_runtime.h>
#include <math.h>

// Problem constants (fixed-shape problem)
#define BN   2
#define CG   32      // channels per border group (128/4)
#define HH   128
#define WW   128
#define HWSZ (HH*WW) // 16384
#define KK   16384   // boxes per batch
#define TK   16      // boxes per block in main kernel

typedef float vf4 __attribute__((ext_vector_type(4)));
typedef _Float16 h8 __attribute__((ext_vector_type(8)));

// pack two f32 -> fp16 pair (RNE via v_cvt_f16_f32), a=low b=high
__device__ inline unsigned int pack_h2(float a, float b) {
  unsigned short ua = __builtin_bit_cast(unsigned short, (_Float16)a);
  unsigned short ub = __builtin_bit_cast(unsigned short, (_Float16)b);
  return (unsigned int)ua | ((unsigned int)ub << 16);
}

// ---------------------------------------------------------------------------
// Kernel 1: transpose+quantize feature [8 slabs][C=32][HW] -> ws fp16 [8][HW][C].
// All 32 channels of one spatial position become one 64B cache line.
// ---------------------------------------------------------------------------
__global__ __launch_bounds__(256) void transpose_f16_kernel(
    const float* __restrict__ feat, unsigned short* __restrict__ ws) {
  __shared__ uint2 lds[128 * 9];           // [i=128][8 quads + 1 pad]
  const int s  = blockIdx.y;               // slab 0..7 (= b*4+g)
  const int i0 = blockIdx.x * 128;         // spatial tile base
  const int t  = threadIdx.x;

  const int iL = (t & 31) * 4;             // 4 consecutive positions
  const int cq = t >> 5;                   // channel quad 0..7

  const float* src = feat + (size_t)s * (CG * HWSZ) + i0 + iL;
  vf4 r[4];
#pragma unroll
  for (int cc = 0; cc < 4; ++cc)
    r[cc] = *(const vf4*)(src + (size_t)(cq * 4 + cc) * HWSZ);

#pragma unroll
  for (int ii = 0; ii < 4; ++ii) {         // register micro-transpose + pack
    uint2 q;
    q.x = pack_h2(r[0][ii], r[1][ii]);
    q.y = pack_h2(r[2][ii], r[3][ii]);
    lds[(iL + ii) * 9 + cq] = q;
  }
  __syncthreads();

  uint2* dst = (uint2*)(ws + ((size_t)s * HWSZ + i0) * CG);
  const int q2 = t & 7;
  const int ih = t >> 3;                   // 0..31
#pragma unroll
  for (int it = 0; it < 4; ++it) {
    const int i = ih + 32 * it;            // 0..127
    dst[i * 8 + q2] = lds[i * 9 + q2];     // 512B contiguous per wave
  }
}

// ---------------------------------------------------------------------------
// Kernel 2: main border-align (fp16 transposed layout).
// Block = 16 boxes, 256 threads = 4 waves; wave w handles border g=w
// (wave-uniform). Lane = oct (t&3, 8 channels) x kk (lane>>2, box 0..15).
// Per corner: 4 lanes x 16B = one 64B line. Bilinear+max in packed fp16.
//
// XCD swizzle: blockIdx round-robins over 8 XCDs (blk&7 = XCD heuristic).
// Map batch = (blk>>2)&1 so batch 0 occupies XCDs 0-3, batch 1 XCDs 4-7:
// each XCD's 4 MiB L2 then holds exactly one batch's 4 MiB slab set.
// ---------------------------------------------------------------------------
__global__ __launch_bounds__(256) void border_align_kernel(
    const unsigned short* __restrict__ wsu, const float* __restrict__ boxes,
    const int* __restrict__ psp, float* __restrict__ out) {
  __shared__ float bxs[TK * 4];
  __shared__ float stf[64];
  __shared__ float lmax[TK * 4 * 33];      // [kg=k*4+g][c], stride 33

  const int blk = blockIdx.x;
  const int b   = (blk >> 2) & 1;          // XCD-partitioned batch
  const int k0  = (((blk >> 3) << 2) | (blk & 3)) * TK;
  const int t   = threadIdx.x;
  const int ps  = *psp;                    // pool_size (10)

  if (t < TK * 4) bxs[t] = boxes[((size_t)b * KK + k0) * 4 + t];
  if (t < 64 && t <= ps) stf[t] = (float)t / (float)ps;  // exact f32 divide
  __syncthreads();

  const int g   = t >> 6;                  // border 0..3 (wave-uniform)
  const int oct = t & 3;                   // channel oct (8 channels)
  const int kk  = (t >> 2) & 15;           // box 0..15
  const bool horiz = (g & 1) == 0;         // g0/g2: x moves; g1/g3: y moves
  const int mshift = horiz ? 0 : 7;        // mov coordinate * (1 or 128)
  const int fshift = horiz ? 7 : 0;        // fix coordinate * (128 or 1)

  const _Float16* slab = (const _Float16*)wsu
      + (size_t)(b * 4 + g) * (HWSZ * CG) + oct * 8;

  const float x1 = bxs[kk * 4 + 0], y1 = bxs[kk * 4 + 1];
  const float x2 = bxs[kk * 4 + 2], y2 = bxs[kk * 4 + 3];
  float mov_s, mov_d, fix;
  if (horiz) { mov_s = x1; mov_d = x2 - x1; fix = (g == 0) ? y1 : y2; }
  else       { mov_s = y1; mov_d = y2 - y1; fix = (g == 1) ? x1 : x2; }
  const bool fok = (fix > -1.0f) && (fix < 128.0f);
  const float fc = fminf(fmaxf(fix, 0.0f), 127.0f);
  const int f0 = (int)fc;
  const float lf = fc - (float)f0;
  const int f1 = min(f0 + 1, 127);
  const int bf0 = f0 << fshift;
  const int bf1 = f1 << fshift;

  h8 acc = (h8)(_Float16)(-65504.0f);      // -inf surrogate (max finite fp16)

  // per-sample address/weight computation
  float lm_c; bool ok_c; int bm0_c, bm1_c;
  auto coords = [&](int p, int& bm0, int& bm1, float& lm, bool& ok) {
    const float mov = fmaf(stf[p], mov_d, mov_s);
    ok = fok && (mov > -1.0f) && (mov < 128.0f);
    const float mc = fminf(fmaxf(mov, 0.0f), 127.0f);
    const int m0 = (int)mc;
    lm = mc - (float)m0;
    const int m1 = min(m0 + 1, 127);
    bm0 = m0 << mshift;
    bm1 = m1 << mshift;
  };

  coords(0, bm0_c, bm1_c, lm_c, ok_c);
  h8 q00 = *(const h8*)(slab + ((size_t)(bf0 + bm0_c) << 5));
  h8 q01 = *(const h8*)(slab + ((size_t)(bf0 + bm1_c) << 5));
  h8 q10 = *(const h8*)(slab + ((size_t)(bf1 + bm0_c) << 5));
  h8 q11 = *(const h8*)(slab + ((size_t)(bf1 + bm1_c) << 5));

  for (int p = 0; p <= ps; ++p) {
    const float lm = lm_c;
    const bool ok = ok_c;
    h8 f00 = q00, f01 = q01, f10 = q10, f11 = q11;
    if (p < ps) {                          // prefetch next sample's corners
      coords(p + 1, bm0_c, bm1_c, lm_c, ok_c);
      q00 = *(const h8*)(slab + ((size_t)(bf0 + bm0_c) << 5));
      q01 = *(const h8*)(slab + ((size_t)(bf0 + bm1_c) << 5));
      q10 = *(const h8*)(slab + ((size_t)(bf1 + bm0_c) << 5));
      q11 = *(const h8*)(slab + ((size_t)(bf1 + bm1_c) << 5));
    }
    const _Float16 w00 = (_Float16)((1.0f - lf) * (1.0f - lm));
    const _Float16 w01 = (_Float16)((1.0f - lf) * lm);
    const _Float16 w10 = (_Float16)(lf * (1.0f - lm));
    const _Float16 w11 = (_Float16)(lf * lm);
    h8 v = f00 * w00 + f01 * w01 + f10 * w10 + f11 * w11;  // v_pk_fma_f16
    v = ok ? v : (h8)(_Float16)0.0f;
    acc = __builtin_elementwise_max(acc, v);               // v_pk_max_f16
  }

  // Stage results as f32: lmax[kg][c], stride 33.
  const int kg = kk * 4 + g;
#pragma unroll
  for (int j = 0; j < 8; ++j)
    lmax[kg * 33 + oct * 8 + j] = (float)acc[j];
  __syncthreads();

  // Coalesced write: out[b][c][k0..k0+15][g]: per c a 256B contiguous run.
  const int kgq = t & 15;                  // float4 index along kg (0..15)
  const int cb  = t >> 4;                  // 0..15
#pragma unroll
  for (int it = 0; it < 2; ++it) {
    const int c = cb + 16 * it;            // 0..31
    vf4 v;
#pragma unroll
    for (int j = 0; j < 4; ++j)
      v[j] = lmax[(kgq * 4 + j) * 33 + c];
    *(vf4*)(out + ((size_t)(b * CG + c) * KK + k0) * 4 + kgq * 4) = v;
  }
}

// ---------------------------------------------------------------------------
// Fallback (ws too small): scalar gather straight from [B,4,C,H,W].
// ---------------------------------------------------------------------------
__global__ __launch_bounds__(128) void border_align_fallback(
    const float* __restrict__ base, const float* __restrict__ boxes,
    const int* __restrict__ psp, float* __restrict__ out) {
  const int blk = blockIdx.x;
  const int b = blk >> 10;
  const int t = threadIdx.x;
  const int g = t >> 5, c = t & 31;
  const int k0 = (blk & 1023) * 16;
  const int ps = *psp;
  const float psf = (float)ps;
  const float* slab = base + (size_t)(b * 4 + g) * (CG * HWSZ) + (size_t)c * HWSZ;
  for (int kk = 0; kk < 16; ++kk) {
    const int kbox = k0 + kk;
    const float x1 = boxes[((size_t)b * KK + kbox) * 4 + 0];
    const float y1 = boxes[((size_t)b * KK + kbox) * 4 + 1];
    const float x2 = boxes[((size_t)b * KK + kbox) * 4 + 2];
    const float y2 = boxes[((size_t)b * KK + kbox) * 4 + 3];
    float m = -INFINITY;
    for (int p = 0; p <= ps; ++p) {
      const float tf = (float)p / psf;
      float x, y;
      if      (g == 0) { x = x1 + tf * (x2 - x1); y = y1; }
      else if (g == 1) { x = x1; y = y1 + tf * (y2 - y1); }
      else if (g == 2) { x = x1 + tf * (x2 - x1); y = y2; }
      else             { x = x2; y = y1 + tf * (y2 - y1); }
      const bool valid = (x > -1.0f) && (x < 128.0f) && (y > -1.0f) && (y < 128.0f);
      const float xc = fminf(fmaxf(x, 0.0f), 127.0f);
      const float yc = fminf(fmaxf(y, 0.0f), 127.0f);
      const int x0 = (int)xc, y0 = (int)yc;
      const float lx = xc - (float)x0, ly = yc - (float)y0;
      const int x1i = min(x0 + 1, 127), y1i = min(y0 + 1, 127);
      const float f00 = slab[y0 * WW + x0],  f01 = slab[y0 * WW + x1i];
      const float f10 = slab[y1i * WW + x0], f11 = slab[y1i * WW + x1i];
      float v = f00 * (1 - ly) * (1 - lx) + f01 * (1 - ly) * lx
              + f10 * ly * (1 - lx) + f11 * ly * lx;
      v = valid ? v : 0.0f;
      m = fmaxf(m, v);
    }
    out[(((size_t)(b * CG + c)) * KK + kbox) * 4 + g] = m;
  }
}

extern "C" void kernel_launch(void* const* d_in, const int* in_sizes, int n_in,
                              void* d_out, int out_size, void* d_ws, size_t ws_size,
                              hipStream_t stream) {
  const float* feature = (const float*)d_in[0];
  const float* boxes   = (const float*)d_in[1];
  const int*   psp     = (const int*)d_in[2];
  float*       out     = (float*)d_out;

  const size_t need = (size_t)BN * 4 * CG * HWSZ * sizeof(unsigned short); // 8 MiB
  if (ws_size >= need) {
    unsigned short* ws = (unsigned short*)d_ws;
    hipLaunchKernelGGL(transpose_f16_kernel, dim3(HWSZ / 128, BN * 4),
                       dim3(256), 0, stream, feature, ws);
    hipLaunchKernelGGL(border_align_kernel, dim3(BN * (KK / TK)), dim3(256), 0,
                       stream, ws, boxes, psp, out);
  } else {
    hipLaunchKernelGGL(border_align_fallback, dim3(BN * (KK / 16)), dim3(128), 0,
                       stream, feature, boxes, psp, out);
  }
}

// Round 8
// 96.486 us; speedup vs baseline: 1.8285x; 1.0002x over previous
//
#include <hip/hip_runtime.h>
#include <math.h>

// Problem constants (fixed-shape problem)
#define BN   2
#define CG   32      // channels per border group (128/4)
#define HH   128
#define WW   128
#define HWSZ (HH*WW) // 16384
#define KK   16384   // boxes per batch
#define TK   16      // boxes per block in main kernel

typedef float vf4 __attribute__((ext_vector_type(4)));
typedef _Float16 h8 __attribute__((ext_vector_type(8)));

// pack two f32 -> fp16 pair (RNE via v_cvt_f16_f32), a=low b=high
__device__ inline unsigned int pack_h2(float a, float b) {
  unsigned short ua = __builtin_bit_cast(unsigned short, (_Float16)a);
  unsigned short ub = __builtin_bit_cast(unsigned short, (_Float16)b);
  return (unsigned int)ua | ((unsigned int)ub << 16);
}

// ---------------------------------------------------------------------------
// Kernel 1: transpose+quantize feature [8 slabs][C=32][HW] -> ws fp16 [8][HW][C].
// All 32 channels of one spatial position become one 64B cache line.
// ---------------------------------------------------------------------------
__global__ __launch_bounds__(256) void transpose_f16_kernel(
    const float* __restrict__ feat, unsigned short* __restrict__ ws) {
  __shared__ uint2 lds[128 * 9];           // [i=128][8 quads + 1 pad]
  const int s  = blockIdx.y;               // slab 0..7 (= b*4+g)
  const int i0 = blockIdx.x * 128;         // spatial tile base
  const int t  = threadIdx.x;

  const int iL = (t & 31) * 4;             // 4 consecutive positions
  const int cq = t >> 5;                   // channel quad 0..7

  const float* src = feat + (size_t)s * (CG * HWSZ) + i0 + iL;
  vf4 r[4];
#pragma unroll
  for (int cc = 0; cc < 4; ++cc)
    r[cc] = *(const vf4*)(src + (size_t)(cq * 4 + cc) * HWSZ);

#pragma unroll
  for (int ii = 0; ii < 4; ++ii) {         // register micro-transpose + pack
    uint2 q;
    q.x = pack_h2(r[0][ii], r[1][ii]);
    q.y = pack_h2(r[2][ii], r[3][ii]);
    lds[(iL + ii) * 9 + cq] = q;
  }
  __syncthreads();

  uint2* dst = (uint2*)(ws + ((size_t)s * HWSZ + i0) * CG);
  const int q2 = t & 7;
  const int ih = t >> 3;                   // 0..31
#pragma unroll
  for (int it = 0; it < 4; ++it) {
    const int i = ih + 32 * it;            // 0..127
    dst[i * 8 + q2] = lds[i * 9 + q2];     // 512B contiguous per wave
  }
}

// ---------------------------------------------------------------------------
// Kernel 2: main border-align (fp16 transposed layout).
// Block = 16 boxes, 256 threads = 4 waves; wave w handles border g=w
// (wave-uniform). Lane = oct (t&3, 8 channels) x kk (lane>>2, box 0..15).
// Per corner: 4 lanes x 16B = one 64B line. Bilinear+max in packed fp16.
// Output stores are nontemporal: written once, never re-read -> keep the
// fp16 ws slab set resident in L2 instead.
// ---------------------------------------------------------------------------
__global__ __launch_bounds__(256) void border_align_kernel(
    const unsigned short* __restrict__ wsu, const float* __restrict__ boxes,
    const int* __restrict__ psp, float* __restrict__ out) {
  __shared__ float bxs[TK * 4];
  __shared__ float stf[64];
  __shared__ float lmax[TK * 4 * 33];      // [kg=k*4+g][c], stride 33

  const int blk = blockIdx.x;
  const int b   = (blk >> 2) & 1;          // XCD-partitioned batch
  const int k0  = (((blk >> 3) << 2) | (blk & 3)) * TK;
  const int t   = threadIdx.x;
  const int ps  = *psp;                    // pool_size (10)

  if (t < TK * 4) bxs[t] = boxes[((size_t)b * KK + k0) * 4 + t];
  if (t < 64 && t <= ps) stf[t] = (float)t / (float)ps;  // exact f32 divide
  __syncthreads();

  const int g   = t >> 6;                  // border 0..3 (wave-uniform)
  const int oct = t & 3;                   // channel oct (8 channels)
  const int kk  = (t >> 2) & 15;           // box 0..15
  const bool horiz = (g & 1) == 0;         // g0/g2: x moves; g1/g3: y moves
  const int mshift = horiz ? 0 : 7;        // mov coordinate * (1 or 128)
  const int fshift = horiz ? 7 : 0;        // fix coordinate * (128 or 1)

  const _Float16* slab = (const _Float16*)wsu
      + (size_t)(b * 4 + g) * (HWSZ * CG) + oct * 8;

  const float x1 = bxs[kk * 4 + 0], y1 = bxs[kk * 4 + 1];
  const float x2 = bxs[kk * 4 + 2], y2 = bxs[kk * 4 + 3];
  float mov_s, mov_d, fix;
  if (horiz) { mov_s = x1; mov_d = x2 - x1; fix = (g == 0) ? y1 : y2; }
  else       { mov_s = y1; mov_d = y2 - y1; fix = (g == 1) ? x1 : x2; }
  const bool fok = (fix > -1.0f) && (fix < 128.0f);
  const float fc = fminf(fmaxf(fix, 0.0f), 127.0f);
  const int f0 = (int)fc;
  const float lf = fc - (float)f0;
  const int f1 = min(f0 + 1, 127);
  const int bf0 = f0 << fshift;
  const int bf1 = f1 << fshift;

  h8 acc = (h8)(_Float16)(-65504.0f);      // -inf surrogate (max finite fp16)

  // per-sample address/weight computation
  float lm_c; bool ok_c; int bm0_c, bm1_c;
  auto coords = [&](int p, int& bm0, int& bm1, float& lm, bool& ok) {
    const float mov = fmaf(stf[p], mov_d, mov_s);
    ok = fok && (mov > -1.0f) && (mov < 128.0f);
    const float mc = fminf(fmaxf(mov, 0.0f), 127.0f);
    const int m0 = (int)mc;
    lm = mc - (float)m0;
    const int m1 = min(m0 + 1, 127);
    bm0 = m0 << mshift;
    bm1 = m1 << mshift;
  };

  coords(0, bm0_c, bm1_c, lm_c, ok_c);
  h8 q00 = *(const h8*)(slab + ((size_t)(bf0 + bm0_c) << 5));
  h8 q01 = *(const h8*)(slab + ((size_t)(bf0 + bm1_c) << 5));
  h8 q10 = *(const h8*)(slab + ((size_t)(bf1 + bm0_c) << 5));
  h8 q11 = *(const h8*)(slab + ((size_t)(bf1 + bm1_c) << 5));

  for (int p = 0; p <= ps; ++p) {
    const float lm = lm_c;
    const bool ok = ok_c;
    h8 f00 = q00, f01 = q01, f10 = q10, f11 = q11;
    if (p < ps) {                          // prefetch next sample's corners
      coords(p + 1, bm0_c, bm1_c, lm_c, ok_c);
      q00 = *(const h8*)(slab + ((size_t)(bf0 + bm0_c) << 5));
      q01 = *(const h8*)(slab + ((size_t)(bf0 + bm1_c) << 5));
      q10 = *(const h8*)(slab + ((size_t)(bf1 + bm0_c) << 5));
      q11 = *(const h8*)(slab + ((size_t)(bf1 + bm1_c) << 5));
    }
    const _Float16 w00 = (_Float16)((1.0f - lf) * (1.0f - lm));
    const _Float16 w01 = (_Float16)((1.0f - lf) * lm);
    const _Float16 w10 = (_Float16)(lf * (1.0f - lm));
    const _Float16 w11 = (_Float16)(lf * lm);
    h8 v = f00 * w00 + f01 * w01 + f10 * w10 + f11 * w11;  // v_pk_fma_f16
    v = ok ? v : (h8)(_Float16)0.0f;
    acc = __builtin_elementwise_max(acc, v);               // v_pk_max_f16
  }

  // Stage results as f32: lmax[kg][c], stride 33.
  const int kg = kk * 4 + g;
#pragma unroll
  for (int j = 0; j < 8; ++j)
    lmax[kg * 33 + oct * 8 + j] = (float)acc[j];
  __syncthreads();

  // Coalesced nontemporal write: out[b][c][k0..k0+15][g]: 256B run per c.
  const int kgq = t & 15;                  // float4 index along kg (0..15)
  const int cb  = t >> 4;                  // 0..15
#pragma unroll
  for (int it = 0; it < 2; ++it) {
    const int c = cb + 16 * it;            // 0..31
    vf4 v;
#pragma unroll
    for (int j = 0; j < 4; ++j)
      v[j] = lmax[(kgq * 4 + j) * 33 + c];
    vf4* dst = (vf4*)(out + ((size_t)(b * CG + c) * KK + k0) * 4 + kgq * 4);
    __builtin_nontemporal_store(v, dst);
  }
}

// ---------------------------------------------------------------------------
// Fallback (ws too small): scalar gather straight from [B,4,C,H,W].
// ---------------------------------------------------------------------------
__global__ __launch_bounds__(128) void border_align_fallback(
    const float* __restrict__ base, const float* __restrict__ boxes,
    const int* __restrict__ psp, float* __restrict__ out) {
  const int blk = blockIdx.x;
  const int b = blk >> 10;
  const int t = threadIdx.x;
  const int g = t >> 5, c = t & 31;
  const int k0 = (blk & 1023) * 16;
  const int ps = *psp;
  const float psf = (float)ps;
  const float* slab = base + (size_t)(b * 4 + g) * (CG * HWSZ) + (size_t)c * HWSZ;
  for (int kk = 0; kk < 16; ++kk) {
    const int kbox = k0 + kk;
    const float x1 = boxes[((size_t)b * KK + kbox) * 4 + 0];
    const float y1 = boxes[((size_t)b * KK + kbox) * 4 + 1];
    const float x2 = boxes[((size_t)b * KK + kbox) * 4 + 2];
    const float y2 = boxes[((size_t)b * KK + kbox) * 4 + 3];
    float m = -INFINITY;
    for (int p = 0; p <= ps; ++p) {
      const float tf = (float)p / psf;
      float x, y;
      if      (g == 0) { x = x1 + tf * (x2 - x1); y = y1; }
      else if (g == 1) { x = x1; y = y1 + tf * (y2 - y1); }
      else if (g == 2) { x = x1 + tf * (x2 - x1); y = y2; }
      else             { x = x2; y = y1 + tf * (y2 - y1); }
      const bool valid = (x > -1.0f) && (x < 128.0f) && (y > -1.0f) && (y < 128.0f);
      const float xc = fminf(fmaxf(x, 0.0f), 127.0f);
      const float yc = fminf(fmaxf(y, 0.0f), 127.0f);
      const int x0 = (int)xc, y0 = (int)yc;
      const float lx = xc - (float)x0, ly = yc - (float)y0;
      const int x1i = min(x0 + 1, 127), y1i = min(y0 + 1, 127);
      const float f00 = slab[y0 * WW + x0],  f01 = slab[y0 * WW + x1i];
      const float f10 = slab[y1i * WW + x0], f11 = slab[y1i * WW + x1i];
      float v = f00 * (1 - ly) * (1 - lx) + f01 * (1 - ly) * lx
              + f10 * ly * (1 - lx) + f11 * ly * lx;
      v = valid ? v : 0.0f;
      m = fmaxf(m, v);
    }
    out[(((size_t)(b * CG + c)) * KK + kbox) * 4 + g] = m;
  }
}

extern "C" void kernel_launch(void* const* d_in, const int* in_sizes, int n_in,
                              void* d_out, int out_size, void* d_ws, size_t ws_size,
                              hipStream_t stream) {
  const float* feature = (const float*)d_in[0];
  const float* boxes   = (const float*)d_in[1];
  const int*   psp     = (const int*)d_in[2];
  float*       out     = (float*)d_out;

  const size_t need = (size_t)BN * 4 * CG * HWSZ * sizeof(unsigned short); // 8 MiB
  if (ws_size >= need) {
    unsigned short* ws = (unsigned short*)d_ws;
    hipLaunchKernelGGL(transpose_f16_kernel, dim3(HWSZ / 128, BN * 4),
                       dim3(256), 0, stream, feature, ws);
    hipLaunchKernelGGL(border_align_kernel, dim3(BN * (KK / TK)), dim3(256), 0,
                       stream, ws, boxes, psp, out);
  } else {
    hipLaunchKernelGGL(border_align_fallback, dim3(BN * (KK / 16)), dim3(128), 0,
                       stream, feature, boxes, psp, out);
  }
}